// Round 5
// baseline (227.689 us; speedup 1.0000x reference)
//
#include <hip/hip_runtime.h>
#include <hip/hip_bf16.h>
#include <stdint.h>

// ---------------------------------------------------------------------------
// y = w4( s1 ),  s1 = (1-g1)*h1 + z1   (s0 == 1 exactly: rowsum(|x|+0.1)>=25.6
//                                       saturates tanh at fp32/fp64)
// Round-4 restructure (pass_b was HBM-traffic-bound: 288MB @2.9TB/s = 99us):
//   - g1,z1 are TILE-LOCAL (xa[m]@U[n], K=256): recompute inside the h-kernel,
//     keep packed bf16 in registers -> g/z never touch HBM (-128MB traffic).
//   - pass_a now computes ONLY r1 (needed as a full row-panel operand).
//   - XCD-chunked swizzle: each XCD owns 16 consecutive m-panels, n fastest,
//     so each r1 panel (256KB) is L2-resident for its 8 n-blocks.
// ---------------------------------------------------------------------------

typedef unsigned short u16;
using f32x4  = __attribute__((ext_vector_type(4))) float;
using bf16x8 = __attribute__((ext_vector_type(8))) short;

#define BATCH 16384
#define NIN   256
#define NHID  1024
#define NOUT  256

#define BM 128
#define BN 128
#define BK 32

__device__ __forceinline__ u16 f2bf(float f) {
  unsigned u = __builtin_bit_cast(unsigned, f);
  unsigned r = 0x7fffu + ((u >> 16) & 1u);
  return (u16)((u + r) >> 16);
}
__device__ __forceinline__ float bf2f(u16 h) {
  unsigned u = ((unsigned)h) << 16;
  return __builtin_bit_cast(float, u);
}
__device__ __forceinline__ float fast_tanh(float x) {
  float cx = fminf(fmaxf(x, -15.f), 15.f);
  float e  = __expf(2.f * cx);
  return (e - 1.f) / (e + 1.f);
}

__device__ __forceinline__ void gload_lds16(const u16* g, u16* l) {
  __builtin_amdgcn_global_load_lds(
      (__attribute__((address_space(1))) void*)(const_cast<u16*>(g)),
      (__attribute__((address_space(3))) void*)(l),
      16, 0, 0);
}

// Stage a 128x32 bf16 tile: 512 x 16B, 256 threads, 2 issues each. Linear LDS.
__device__ __forceinline__ void stage_tile(const u16* g0, int ld, u16* lds) {
  int t = threadIdx.x;
#pragma unroll
  for (int iss = 0; iss < 2; ++iss) {
    int idx = t + iss * 256;
    int row = idx >> 2;
    int c   = (idx & 3) << 3;
    gload_lds16(g0 + (size_t)row * ld + c, lds + (size_t)idx * 8);
  }
}

__device__ __forceinline__ void mfma_step(const u16* As, const u16* Bs,
                                          int wm, int wn, int lane,
                                          f32x4 acc[4][4]) {
  int r  = lane & 15;
  int kc = (lane >> 4) << 3;
  bf16x8 a[4], b[4];
#pragma unroll
  for (int i = 0; i < 4; ++i)
    a[i] = *(const bf16x8*)(As + (size_t)((wm + i * 16 + r) * BK + kc));
#pragma unroll
  for (int j = 0; j < 4; ++j)
    b[j] = *(const bf16x8*)(Bs + (size_t)((wn + j * 16 + r) * BK + kc));
#pragma unroll
  for (int i = 0; i < 4; ++i)
#pragma unroll
    for (int j = 0; j < 4; ++j)
      acc[i][j] = __builtin_amdgcn_mfma_f32_16x16x32_bf16(a[i], b[j], acc[i][j], 0, 0, 0);
}

__device__ __forceinline__ void gemm_seg(const u16* A, int lda,
                                         const u16* B, int ldb, int K,
                                         int m0, int n0, u16* As, u16* Bs,
                                         int wm, int wn, int lane,
                                         f32x4 acc[4][4]) {
  const u16* At = A + (size_t)m0 * lda;
  const u16* Bt = B + (size_t)n0 * ldb;
  for (int kt = 0; kt < K; kt += BK) {
    stage_tile(At + kt, lda, As);
    stage_tile(Bt + kt, ldb, Bs);
    __syncthreads();
    mfma_step(As, Bs, wm, wn, lane, acc);
    __syncthreads();
  }
}

__device__ __forceinline__ void zero_acc(f32x4 acc[4][4]) {
  f32x4 z = {0.f, 0.f, 0.f, 0.f};
#pragma unroll
  for (int i = 0; i < 4; ++i)
#pragma unroll
    for (int j = 0; j < 4; ++j) acc[i][j] = z;
}

// --------------------------- prep kernels ----------------------------------

__global__ void k_prep_x(const float* __restrict__ x, u16* __restrict__ xa) {
  int i = blockIdx.x * 256 + threadIdx.x;
  float4 v = ((const float4*)x)[i];
  ushort4 o;
  o.x = f2bf(fabsf(v.x) + 0.1f);
  o.y = f2bf(fabsf(v.y) + 0.1f);
  o.z = f2bf(fabsf(v.z) + 0.1f);
  o.w = f2bf(fabsf(v.w) + 0.1f);
  ((ushort4*)xa)[i] = o;
}

struct WCvt { const float* src[6]; u16* dst[6]; int n[6]; };
__global__ void k_cvt(WCvt a) {
  int k = blockIdx.y;
  int i = blockIdx.x * 256 + threadIdx.x;
  if (i * 4 < a.n[k]) {
    float4 v = ((const float4*)a.src[k])[i];
    ushort4 o;
    o.x = f2bf(v.x); o.y = f2bf(v.y); o.z = f2bf(v.z); o.w = f2bf(v.w);
    ((ushort4*)a.dst[k])[i] = o;
  }
}

// c[n] = sum_k W[n,k] + b[n]  (s0==1 collapse of s0@W.T)
struct WSum { const float* w[3]; const float* b[3]; float* c[3]; };
__global__ void k_wsum(WSum a) {
  int g = blockIdx.y, n = blockIdx.x;
  const float* row = a.w[g] + (size_t)n * NHID;
  float s = 0.f;
  for (int k = threadIdx.x; k < NHID; k += 256) s += row[k];
#pragma unroll
  for (int o = 32; o; o >>= 1) s += __shfl_down(s, o, 64);
  __shared__ float sm[4];
  if ((threadIdx.x & 63) == 0) sm[threadIdx.x >> 6] = s;
  __syncthreads();
  if (threadIdx.x == 0) a.c[g][n] = sm[0] + sm[1] + sm[2] + sm[3] + a.b[g][n];
}

// --------------------------- GEMM passes -----------------------------------

// r1 = tanh(xa @ ur.T + cr)
__global__ __launch_bounds__(256) void k_pass_r(const u16* __restrict__ xa,
                                                const u16* __restrict__ ur,
                                                const float* __restrict__ cr,
                                                u16* __restrict__ r1) {
  __shared__ __align__(16) u16 As[BM * BK];
  __shared__ __align__(16) u16 Bs[BN * BK];
  int m0 = blockIdx.y * BM, n0 = blockIdx.x * BN;
  int lane = threadIdx.x & 63, wave = threadIdx.x >> 6;
  int wm = (wave >> 1) * 64, wn = (wave & 1) * 64;
  f32x4 acc[4][4];
  zero_acc(acc);
  gemm_seg(xa, NIN, ur, NIN, NIN, m0, n0, As, Bs, wm, wn, lane, acc);

  int crw = (lane >> 4) * 4, cc = lane & 15;
#pragma unroll
  for (int ni = 0; ni < 4; ++ni) {
    int col = n0 + wn + ni * 16 + cc;
    float bias = cr[col];
#pragma unroll
    for (int mi = 0; mi < 4; ++mi)
#pragma unroll
      for (int r = 0; r < 4; ++r) {
        int row = m0 + wm + mi * 16 + crw + r;
        r1[(size_t)row * NHID + col] = f2bf(fast_tanh(acc[mi][ni][r] + bias));
      }
  }
}

// Fused: g1,z1 recomputed in-tile (K=256 each), h1 (K=256+1024), epilogue s1.
//   pg = 1 - tanh(xa@ug + cg)   packed bf16 in regs
//   pz =     tanh(xa@uz + cz)   packed bf16 in regs
//   h  =     tanh(xa@uh + r1@wh + bh)
//   s1 = pg * h + pz
__global__ __launch_bounds__(256) void k_gates_h(
    const u16* __restrict__ xa,
    const u16* __restrict__ ug, const u16* __restrict__ uz,
    const u16* __restrict__ uh,
    const float* __restrict__ cg, const float* __restrict__ cz,
    const float* __restrict__ bh,
    const u16* __restrict__ r1, const u16* __restrict__ wh,
    u16* __restrict__ s1) {
  __shared__ __align__(16) u16 As[BM * BK];
  __shared__ __align__(16) u16 Bs[BN * BK];

  // XCD-chunked swizzle: grid 1024 blocks, 8 XCDs. XCD k gets m-panels
  // [16k,16k+16), n fastest -> r1 panel (256KB) L2-resident for 8 uses.
  int wg  = blockIdx.x;
  int xcd = wg & 7;
  int idx = wg >> 3;          // 0..127
  int mb  = xcd * 16 + (idx >> 3);
  int nb  = idx & 7;
  int m0 = mb * BM, n0 = nb * BN;

  int lane = threadIdx.x & 63, wave = threadIdx.x >> 6;
  int wm = (wave >> 1) * 64, wn = (wave & 1) * 64;
  int crw = (lane >> 4) * 4, cc = lane & 15;

  f32x4 acc[4][4];
  unsigned pg[4][4][2], pz[4][4][2];   // packed bf16 pairs, static idx only

  // ---- gate g ----
  zero_acc(acc);
  gemm_seg(xa, NIN, ug, NIN, NIN, m0, n0, As, Bs, wm, wn, lane, acc);
#pragma unroll
  for (int ni = 0; ni < 4; ++ni) {
    float cv = cg[n0 + wn + ni * 16 + cc];
#pragma unroll
    for (int mi = 0; mi < 4; ++mi) {
      float v0 = 1.f - fast_tanh(acc[mi][ni][0] + cv);
      float v1 = 1.f - fast_tanh(acc[mi][ni][1] + cv);
      float v2 = 1.f - fast_tanh(acc[mi][ni][2] + cv);
      float v3 = 1.f - fast_tanh(acc[mi][ni][3] + cv);
      pg[mi][ni][0] = (unsigned)f2bf(v0) | ((unsigned)f2bf(v1) << 16);
      pg[mi][ni][1] = (unsigned)f2bf(v2) | ((unsigned)f2bf(v3) << 16);
    }
  }

  // ---- gate z ----
  zero_acc(acc);
  gemm_seg(xa, NIN, uz, NIN, NIN, m0, n0, As, Bs, wm, wn, lane, acc);
#pragma unroll
  for (int ni = 0; ni < 4; ++ni) {
    float cv = cz[n0 + wn + ni * 16 + cc];
#pragma unroll
    for (int mi = 0; mi < 4; ++mi) {
      float v0 = fast_tanh(acc[mi][ni][0] + cv);
      float v1 = fast_tanh(acc[mi][ni][1] + cv);
      float v2 = fast_tanh(acc[mi][ni][2] + cv);
      float v3 = fast_tanh(acc[mi][ni][3] + cv);
      pz[mi][ni][0] = (unsigned)f2bf(v0) | ((unsigned)f2bf(v1) << 16);
      pz[mi][ni][1] = (unsigned)f2bf(v2) | ((unsigned)f2bf(v3) << 16);
    }
  }

  // ---- h ----
  zero_acc(acc);
  gemm_seg(xa, NIN, uh, NIN, NIN, m0, n0, As, Bs, wm, wn, lane, acc);
  gemm_seg(r1, NHID, wh, NHID, NHID, m0, n0, As, Bs, wm, wn, lane, acc);

#pragma unroll
  for (int ni = 0; ni < 4; ++ni) {
    int col = n0 + wn + ni * 16 + cc;
    float bias = bh[col];
#pragma unroll
    for (int mi = 0; mi < 4; ++mi)
#pragma unroll
      for (int r = 0; r < 4; ++r) {
        int row = m0 + wm + mi * 16 + crw + r;
        float h = fast_tanh(acc[mi][ni][r] + bias);
        unsigned pgw = pg[mi][ni][r >> 1];
        unsigned pzw = pz[mi][ni][r >> 1];
        u16 pgh = (r & 1) ? (u16)(pgw >> 16) : (u16)(pgw & 0xffff);
        u16 pzh = (r & 1) ? (u16)(pzw >> 16) : (u16)(pzw & 0xffff);
        float s = bf2f(pgh) * h + bf2f(pzh);
        s1[(size_t)row * NHID + col] = f2bf(s);
      }
  }
}

// y = s1 @ w4.T (fp32 out)
__global__ __launch_bounds__(256) void k_pass_c(const u16* __restrict__ s1,
                                                const u16* __restrict__ w4,
                                                float* __restrict__ y) {
  __shared__ __align__(16) u16 As[BM * BK];
  __shared__ __align__(16) u16 Bs[BN * BK];
  int m0 = blockIdx.y * BM, n0 = blockIdx.x * BN;
  int lane = threadIdx.x & 63, wave = threadIdx.x >> 6;
  int wm = (wave >> 1) * 64, wn = (wave & 1) * 64;
  f32x4 acc[4][4];
  zero_acc(acc);
  gemm_seg(s1, NHID, w4, NHID, NHID, m0, n0, As, Bs, wm, wn, lane, acc);

  int crw = (lane >> 4) * 4, cc = lane & 15;
#pragma unroll
  for (int ni = 0; ni < 4; ++ni) {
    int col = n0 + wn + ni * 16 + cc;
#pragma unroll
    for (int mi = 0; mi < 4; ++mi)
#pragma unroll
      for (int r = 0; r < 4; ++r) {
        int row = m0 + wm + mi * 16 + crw + r;
        y[(size_t)row * NOUT + col] = acc[mi][ni][r];
      }
  }
}

// --------------------------- host ------------------------------------------

extern "C" void kernel_launch(void* const* d_in, const int* in_sizes, int n_in,
                              void* d_out, int out_size, void* d_ws, size_t ws_size,
                              hipStream_t stream) {
  (void)in_sizes; (void)n_in; (void)out_size; (void)ws_size;

  const float* x    = (const float*)d_in[0];
  const float* ug1  = (const float*)d_in[3];
  const float* wg1w = (const float*)d_in[4];
  const float* wg1b = (const float*)d_in[5];
  const float* uz1  = (const float*)d_in[6];
  const float* wz1w = (const float*)d_in[7];
  const float* wz1b = (const float*)d_in[8];
  const float* ur1  = (const float*)d_in[9];
  const float* wr1w = (const float*)d_in[10];
  const float* wr1b = (const float*)d_in[11];
  const float* uh1  = (const float*)d_in[12];
  const float* wh1w = (const float*)d_in[13];
  const float* wh1b = (const float*)d_in[14];
  const float* w4   = (const float*)d_in[27];
  float* y = (float*)d_out;

  uint8_t* ws = (uint8_t*)d_ws;
  size_t off = 0;
  auto carve = [&](size_t bytes) -> void* {
    void* p = ws + off;
    off += (bytes + 255) & ~(size_t)255;
    return p;
  };
  u16* xa  = (u16*)carve((size_t)BATCH * NIN * 2);    //  8 MB
  u16* r1  = (u16*)carve((size_t)BATCH * NHID * 2);   // 32 MB
  u16* s1  = (u16*)carve((size_t)BATCH * NHID * 2);   // 32 MB
  u16* bug = (u16*)carve((size_t)NHID * NIN * 2);
  u16* buz = (u16*)carve((size_t)NHID * NIN * 2);
  u16* bur = (u16*)carve((size_t)NHID * NIN * 2);
  u16* buh = (u16*)carve((size_t)NHID * NIN * 2);
  u16* bwh = (u16*)carve((size_t)NHID * NHID * 2);
  u16* bw4 = (u16*)carve((size_t)NOUT * NHID * 2);
  float* cg = (float*)carve(NHID * 4);
  float* cz = (float*)carve(NHID * 4);
  float* cr = (float*)carve(NHID * 4);

  k_prep_x<<<(BATCH * NIN) / (256 * 4), 256, 0, stream>>>(x, xa);

  WCvt wc;
  wc.src[0] = ug1;  wc.dst[0] = bug; wc.n[0] = NHID * NIN;
  wc.src[1] = uz1;  wc.dst[1] = buz; wc.n[1] = NHID * NIN;
  wc.src[2] = ur1;  wc.dst[2] = bur; wc.n[2] = NHID * NIN;
  wc.src[3] = uh1;  wc.dst[3] = buh; wc.n[3] = NHID * NIN;
  wc.src[4] = wh1w; wc.dst[4] = bwh; wc.n[4] = NHID * NHID;
  wc.src[5] = w4;   wc.dst[5] = bw4; wc.n[5] = NOUT * NHID;
  k_cvt<<<dim3(1024, 6), 256, 0, stream>>>(wc);

  WSum wsm;
  wsm.w[0] = wg1w; wsm.b[0] = wg1b; wsm.c[0] = cg;
  wsm.w[1] = wz1w; wsm.b[1] = wz1b; wsm.c[1] = cz;
  wsm.w[2] = wr1w; wsm.b[2] = wr1b; wsm.c[2] = cr;
  k_wsum<<<dim3(1024, 3), 256, 0, stream>>>(wsm);

  k_pass_r<<<dim3(NHID / BN, BATCH / BM), 256, 0, stream>>>(xa, bur, cr, r1);

  k_gates_h<<<(NHID / BN) * (BATCH / BM), 256, 0, stream>>>(
      xa, bug, buz, buh, cg, cz, wh1b, r1, bwh, s1);

  k_pass_c<<<dim3(NOUT / BN, BATCH / BM), 256, 0, stream>>>(s1, bw4, y);
}

// Round 7
// 181.186 us; speedup vs baseline: 1.2567x; 1.2567x over previous
//
#include <hip/hip_runtime.h>
#include <hip/hip_bf16.h>
#include <stdint.h>

// ---------------------------------------------------------------------------
// y = w4( s1 ),  s1 = (1-g1)*h1 + z1   (s0 == 1 exactly: rowsum(|x|+0.1)>=25.6
//                                       saturates tanh in fp32/fp64)
// R5 fused g/z into the h-kernel (traffic 288->114MB) but went latency-bound:
//   VGPR 204 -> 2 blocks/CU, and stage->syncthreads(vmcnt0)->mfma exposed full
//   HBM latency per K-step (171us @ 663GB/s, MfmaUtil 14%).
// R6: minimum-2-phase pipeline (T3/T4): double-buffered LDS, BK=64, issue
//   stage(t+1) before compute(t), counted vmcnt(8) + raw s_barrier -> load
//   latency hides under compute regardless of occupancy. 56 -> 28 K-steps.
// ---------------------------------------------------------------------------

typedef unsigned short u16;
using f32x4  = __attribute__((ext_vector_type(4))) float;
using bf16x8 = __attribute__((ext_vector_type(8))) short;

#define BATCH 16384
#define NIN   256
#define NHID  1024
#define NOUT  256

#define BM 128
#define BN 128
#define BK2 64   // K-chunk per pipeline step

__device__ __forceinline__ u16 f2bf(float f) {
  unsigned u = __builtin_bit_cast(unsigned, f);
  unsigned r = 0x7fffu + ((u >> 16) & 1u);
  return (u16)((u + r) >> 16);
}
__device__ __forceinline__ float bf2f(u16 h) {
  unsigned u = ((unsigned)h) << 16;
  return __builtin_bit_cast(float, u);
}
__device__ __forceinline__ float fast_tanh(float x) {
  float cx = fminf(fmaxf(x, -15.f), 15.f);
  float e  = __expf(2.f * cx);
  return (e - 1.f) / (e + 1.f);
}

__device__ __forceinline__ void gload_lds16(const u16* g, u16* l) {
  __builtin_amdgcn_global_load_lds(
      (__attribute__((address_space(1))) void*)(const_cast<u16*>(g)),
      (__attribute__((address_space(3))) void*)(l),
      16, 0, 0);
}

// Stage a 128x64 bf16 tile (16KB): 1024 granules of 16B, 256 thr x 4 issues.
// LDS dest linear in threadIdx (wave-uniform base + lane*16 per issue).
__device__ __forceinline__ void stage64(const u16* g0, int ld, u16* lds) {
  int t = threadIdx.x;
#pragma unroll
  for (int iss = 0; iss < 4; ++iss) {
    int idx = t + iss * 256;        // granule 0..1023
    int row = idx >> 3;             // 8 granules (128B) per row
    int c   = (idx & 7) << 3;       // bf16 elem offset
    gload_lds16(g0 + (size_t)row * ld + c, lds + (size_t)idx * 8);
  }
}

// One BK2=64 step: 32 MFMA per wave (4x4 frags x 2 k-chunks).
__device__ __forceinline__ void mfma64(const u16* As, const u16* Bs,
                                       int wm, int wn, int lane,
                                       f32x4 acc[4][4]) {
  int r  = lane & 15;
  int kq = (lane >> 4) << 3;
#pragma unroll
  for (int ks = 0; ks < 2; ++ks) {
    int kc = ks * 32 + kq;
    bf16x8 a[4], b[4];
#pragma unroll
    for (int i = 0; i < 4; ++i)
      a[i] = *(const bf16x8*)(As + (size_t)((wm + i * 16 + r) * BK2 + kc));
#pragma unroll
    for (int j = 0; j < 4; ++j)
      b[j] = *(const bf16x8*)(Bs + (size_t)((wn + j * 16 + r) * BK2 + kc));
#pragma unroll
    for (int i = 0; i < 4; ++i)
#pragma unroll
      for (int j = 0; j < 4; ++j)
        acc[i][j] = __builtin_amdgcn_mfma_f32_16x16x32_bf16(a[i], b[j], acc[i][j], 0, 0, 0);
  }
}

// One pipeline step: issue next-tile stage, wait CURRENT tile (vmcnt(8): next's
// 8 loads stay in flight), barrier, compute, drain own ds_reads, barrier.
__device__ __forceinline__ void pipe_step(const u16* At, int lda,
                                          const u16* Bt, int ldb,
                                          int t, int STEPS,
                                          u16* Ac, u16* Bc, u16* An, u16* Bn,
                                          int wm, int wn, int lane,
                                          f32x4 acc[4][4]) {
  if (t + 1 < STEPS) {
    stage64(At + (size_t)(t + 1) * BK2, lda, An);
    stage64(Bt + (size_t)(t + 1) * BK2, ldb, Bn);
    asm volatile("s_waitcnt vmcnt(8)" ::: "memory");
  } else {
    asm volatile("s_waitcnt vmcnt(0)" ::: "memory");
  }
  __builtin_amdgcn_s_barrier();
  mfma64(Ac, Bc, wm, wn, lane, acc);
  asm volatile("s_waitcnt lgkmcnt(0)" ::: "memory");
  __builtin_amdgcn_s_barrier();
}

// A: MxK row-major(lda), B: NxK row-major(ldb) -> acc += A@B.T (tile m0,n0).
// smem layout: As0 | Bs0 | As1 | Bs1, 8192 u16 (16KB) each.
template<int STEPS>
__device__ __forceinline__ void gemm_pipe(const u16* A, int lda,
                                          const u16* B, int ldb,
                                          int m0, int n0, u16* sm,
                                          int wm, int wn, int lane,
                                          f32x4 acc[4][4]) {
  const u16* At = A + (size_t)m0 * lda;
  const u16* Bt = B + (size_t)n0 * ldb;
  u16* As0 = sm;          u16* Bs0 = sm + 8192;
  u16* As1 = sm + 16384;  u16* Bs1 = sm + 24576;
  stage64(At, lda, As0);
  stage64(Bt, ldb, Bs0);
  static_assert(STEPS % 2 == 0, "even steps");
#pragma unroll
  for (int tt = 0; tt < STEPS / 2; ++tt) {
    pipe_step(At, lda, Bt, ldb, 2 * tt,     STEPS, As0, Bs0, As1, Bs1, wm, wn, lane, acc);
    pipe_step(At, lda, Bt, ldb, 2 * tt + 1, STEPS, As1, Bs1, As0, Bs0, wm, wn, lane, acc);
  }
}

__device__ __forceinline__ void zero_acc(f32x4 acc[4][4]) {
  f32x4 z = {0.f, 0.f, 0.f, 0.f};
#pragma unroll
  for (int i = 0; i < 4; ++i)
#pragma unroll
    for (int j = 0; j < 4; ++j) acc[i][j] = z;
}

// --------------------------- prep kernels ----------------------------------

__global__ void k_prep_x(const float* __restrict__ x, u16* __restrict__ xa) {
  int i = blockIdx.x * 256 + threadIdx.x;
  float4 v = ((const float4*)x)[i];
  ushort4 o;
  o.x = f2bf(fabsf(v.x) + 0.1f);
  o.y = f2bf(fabsf(v.y) + 0.1f);
  o.z = f2bf(fabsf(v.z) + 0.1f);
  o.w = f2bf(fabsf(v.w) + 0.1f);
  ((ushort4*)xa)[i] = o;
}

struct WCvt { const float* src[6]; u16* dst[6]; int n[6]; };
__global__ void k_cvt(WCvt a) {
  int k = blockIdx.y;
  int i = blockIdx.x * 256 + threadIdx.x;
  if (i * 4 < a.n[k]) {
    float4 v = ((const float4*)a.src[k])[i];
    ushort4 o;
    o.x = f2bf(v.x); o.y = f2bf(v.y); o.z = f2bf(v.z); o.w = f2bf(v.w);
    ((ushort4*)a.dst[k])[i] = o;
  }
}

// c[n] = sum_k W[n,k] + b[n]  (s0==1 collapse of s0@W.T)
struct WSum { const float* w[3]; const float* b[3]; float* c[3]; };
__global__ void k_wsum(WSum a) {
  int g = blockIdx.y, n = blockIdx.x;
  const float* row = a.w[g] + (size_t)n * NHID;
  float s = 0.f;
  for (int k = threadIdx.x; k < NHID; k += 256) s += row[k];
#pragma unroll
  for (int o = 32; o; o >>= 1) s += __shfl_down(s, o, 64);
  __shared__ float sm[4];
  if ((threadIdx.x & 63) == 0) sm[threadIdx.x >> 6] = s;
  __syncthreads();
  if (threadIdx.x == 0) a.c[g][n] = sm[0] + sm[1] + sm[2] + sm[3] + a.b[g][n];
}

// --------------------------- GEMM passes -----------------------------------

// r1 = tanh(xa @ ur.T + cr)
__global__ __launch_bounds__(256) void k_pass_r(const u16* __restrict__ xa,
                                                const u16* __restrict__ ur,
                                                const float* __restrict__ cr,
                                                u16* __restrict__ r1) {
  __shared__ __align__(16) u16 smem[32768];
  int m0 = blockIdx.y * BM, n0 = blockIdx.x * BN;
  int lane = threadIdx.x & 63, wave = threadIdx.x >> 6;
  int wm = (wave >> 1) * 64, wn = (wave & 1) * 64;
  f32x4 acc[4][4];
  zero_acc(acc);
  gemm_pipe<4>(xa, NIN, ur, NIN, m0, n0, smem, wm, wn, lane, acc);

  int crw = (lane >> 4) * 4, cc = lane & 15;
#pragma unroll
  for (int ni = 0; ni < 4; ++ni) {
    int col = n0 + wn + ni * 16 + cc;
    float bias = cr[col];
#pragma unroll
    for (int mi = 0; mi < 4; ++mi)
#pragma unroll
      for (int r = 0; r < 4; ++r) {
        int row = m0 + wm + mi * 16 + crw + r;
        r1[(size_t)row * NHID + col] = f2bf(fast_tanh(acc[mi][ni][r] + bias));
      }
  }
}

// Fused: pg=1-tanh(xa@ug+cg), pz=tanh(xa@uz+cz) in regs (packed bf16);
//        h=tanh(xa@uh + r1@wh + bh);  s1 = pg*h + pz.
__global__ __launch_bounds__(256) void k_gates_h(
    const u16* __restrict__ xa,
    const u16* __restrict__ ug, const u16* __restrict__ uz,
    const u16* __restrict__ uh,
    const float* __restrict__ cg, const float* __restrict__ cz,
    const float* __restrict__ bh,
    const u16* __restrict__ r1, const u16* __restrict__ wh,
    u16* __restrict__ s1) {
  __shared__ __align__(16) u16 smem[32768];

  // XCD-chunked swizzle: XCD k owns m-panels [16k,16k+16), n fastest ->
  // r1 panel (256KB) stays L2-resident across its 8 n-blocks.
  int wg  = blockIdx.x;
  int xcd = wg & 7;
  int idx = wg >> 3;
  int mb  = xcd * 16 + (idx >> 3);
  int nb  = idx & 7;
  int m0 = mb * BM, n0 = nb * BN;

  int lane = threadIdx.x & 63, wave = threadIdx.x >> 6;
  int wm = (wave >> 1) * 64, wn = (wave & 1) * 64;
  int crw = (lane >> 4) * 4, cc = lane & 15;

  f32x4 acc[4][4];
  unsigned pg[4][4][2], pz[4][4][2];   // packed bf16 pairs, static idx only

  // ---- gate g ----
  zero_acc(acc);
  gemm_pipe<4>(xa, NIN, ug, NIN, m0, n0, smem, wm, wn, lane, acc);
#pragma unroll
  for (int ni = 0; ni < 4; ++ni) {
    float cv = cg[n0 + wn + ni * 16 + cc];
#pragma unroll
    for (int mi = 0; mi < 4; ++mi) {
      float v0 = 1.f - fast_tanh(acc[mi][ni][0] + cv);
      float v1 = 1.f - fast_tanh(acc[mi][ni][1] + cv);
      float v2 = 1.f - fast_tanh(acc[mi][ni][2] + cv);
      float v3 = 1.f - fast_tanh(acc[mi][ni][3] + cv);
      pg[mi][ni][0] = (unsigned)f2bf(v0) | ((unsigned)f2bf(v1) << 16);
      pg[mi][ni][1] = (unsigned)f2bf(v2) | ((unsigned)f2bf(v3) << 16);
    }
  }

  // ---- gate z ----
  zero_acc(acc);
  gemm_pipe<4>(xa, NIN, uz, NIN, m0, n0, smem, wm, wn, lane, acc);
#pragma unroll
  for (int ni = 0; ni < 4; ++ni) {
    float cv = cz[n0 + wn + ni * 16 + cc];
#pragma unroll
    for (int mi = 0; mi < 4; ++mi) {
      float v0 = fast_tanh(acc[mi][ni][0] + cv);
      float v1 = fast_tanh(acc[mi][ni][1] + cv);
      float v2 = fast_tanh(acc[mi][ni][2] + cv);
      float v3 = fast_tanh(acc[mi][ni][3] + cv);
      pz[mi][ni][0] = (unsigned)f2bf(v0) | ((unsigned)f2bf(v1) << 16);
      pz[mi][ni][1] = (unsigned)f2bf(v2) | ((unsigned)f2bf(v3) << 16);
    }
  }

  // ---- h ----
  zero_acc(acc);
  gemm_pipe<4>(xa, NIN, uh, NIN, m0, n0, smem, wm, wn, lane, acc);
  gemm_pipe<16>(r1, NHID, wh, NHID, m0, n0, smem, wm, wn, lane, acc);

#pragma unroll
  for (int ni = 0; ni < 4; ++ni) {
    int col = n0 + wn + ni * 16 + cc;
    float bias = bh[col];
#pragma unroll
    for (int mi = 0; mi < 4; ++mi)
#pragma unroll
      for (int r = 0; r < 4; ++r) {
        int row = m0 + wm + mi * 16 + crw + r;
        float h = fast_tanh(acc[mi][ni][r] + bias);
        unsigned pgw = pg[mi][ni][r >> 1];
        unsigned pzw = pz[mi][ni][r >> 1];
        u16 pgh = (r & 1) ? (u16)(pgw >> 16) : (u16)(pgw & 0xffff);
        u16 pzh = (r & 1) ? (u16)(pzw >> 16) : (u16)(pzw & 0xffff);
        float s = bf2f(pgh) * h + bf2f(pzh);
        s1[(size_t)row * NHID + col] = f2bf(s);
      }
  }
}

// y = s1 @ w4.T (fp32 out)
__global__ __launch_bounds__(256) void k_pass_c(const u16* __restrict__ s1,
                                                const u16* __restrict__ w4,
                                                float* __restrict__ y) {
  __shared__ __align__(16) u16 smem[32768];
  int m0 = blockIdx.y * BM, n0 = blockIdx.x * BN;
  int lane = threadIdx.x & 63, wave = threadIdx.x >> 6;
  int wm = (wave >> 1) * 64, wn = (wave & 1) * 64;
  f32x4 acc[4][4];
  zero_acc(acc);
  gemm_pipe<16>(s1, NHID, w4, NHID, m0, n0, smem, wm, wn, lane, acc);

  int crw = (lane >> 4) * 4, cc = lane & 15;
#pragma unroll
  for (int ni = 0; ni < 4; ++ni) {
    int col = n0 + wn + ni * 16 + cc;
#pragma unroll
    for (int mi = 0; mi < 4; ++mi)
#pragma unroll
      for (int r = 0; r < 4; ++r) {
        int row = m0 + wm + mi * 16 + crw + r;
        y[(size_t)row * NOUT + col] = acc[mi][ni][r];
      }
  }
}

// --------------------------- host ------------------------------------------

extern "C" void kernel_launch(void* const* d_in, const int* in_sizes, int n_in,
                              void* d_out, int out_size, void* d_ws, size_t ws_size,
                              hipStream_t stream) {
  (void)in_sizes; (void)n_in; (void)out_size; (void)ws_size;

  const float* x    = (const float*)d_in[0];
  const float* ug1  = (const float*)d_in[3];
  const float* wg1w = (const float*)d_in[4];
  const float* wg1b = (const float*)d_in[5];
  const float* uz1  = (const float*)d_in[6];
  const float* wz1w = (const float*)d_in[7];
  const float* wz1b = (const float*)d_in[8];
  const float* ur1  = (const float*)d_in[9];
  const float* wr1w = (const float*)d_in[10];
  const float* wr1b = (const float*)d_in[11];
  const float* uh1  = (const float*)d_in[12];
  const float* wh1w = (const float*)d_in[13];
  const float* wh1b = (const float*)d_in[14];
  const float* w4   = (const float*)d_in[27];
  float* y = (float*)d_out;

  uint8_t* ws = (uint8_t*)d_ws;
  size_t off = 0;
  auto carve = [&](size_t bytes) -> void* {
    void* p = ws + off;
    off += (bytes + 255) & ~(size_t)255;
    return p;
  };
  u16* xa  = (u16*)carve((size_t)BATCH * NIN * 2);    //  8 MB
  u16* r1  = (u16*)carve((size_t)BATCH * NHID * 2);   // 32 MB
  u16* s1  = (u16*)carve((size_t)BATCH * NHID * 2);   // 32 MB
  u16* bug = (u16*)carve((size_t)NHID * NIN * 2);
  u16* buz = (u16*)carve((size_t)NHID * NIN * 2);
  u16* bur = (u16*)carve((size_t)NHID * NIN * 2);
  u16* buh = (u16*)carve((size_t)NHID * NIN * 2);
  u16* bwh = (u16*)carve((size_t)NHID * NHID * 2);
  u16* bw4 = (u16*)carve((size_t)NOUT * NHID * 2);
  float* cg = (float*)carve(NHID * 4);
  float* cz = (float*)carve(NHID * 4);
  float* cr = (float*)carve(NHID * 4);

  k_prep_x<<<(BATCH * NIN) / (256 * 4), 256, 0, stream>>>(x, xa);

  WCvt wc;
  wc.src[0] = ug1;  wc.dst[0] = bug; wc.n[0] = NHID * NIN;
  wc.src[1] = uz1;  wc.dst[1] = buz; wc.n[1] = NHID * NIN;
  wc.src[2] = ur1;  wc.dst[2] = bur; wc.n[2] = NHID * NIN;
  wc.src[3] = uh1;  wc.dst[3] = buh; wc.n[3] = NHID * NIN;
  wc.src[4] = wh1w; wc.dst[4] = bwh; wc.n[4] = NHID * NHID;
  wc.src[5] = w4;   wc.dst[5] = bw4; wc.n[5] = NOUT * NHID;
  k_cvt<<<dim3(1024, 6), 256, 0, stream>>>(wc);

  WSum wsm;
  wsm.w[0] = wg1w; wsm.b[0] = wg1b; wsm.c[0] = cg;
  wsm.w[1] = wz1w; wsm.b[1] = wz1b; wsm.c[1] = cz;
  wsm.w[2] = wr1w; wsm.b[2] = wr1b; wsm.c[2] = cr;
  k_wsum<<<dim3(1024, 3), 256, 0, stream>>>(wsm);

  k_pass_r<<<dim3(NHID / BN, BATCH / BM), 256, 0, stream>>>(xa, bur, cr, r1);

  k_gates_h<<<(NHID / BN) * (BATCH / BM), 256, 0, stream>>>(
      xa, bug, buz, buh, cg, cz, wh1b, r1, bwh, s1);

  k_pass_c<<<dim3(NOUT / BN, BATCH / BM), 256, 0, stream>>>(s1, bw4, y);
}

// Round 8
// 155.639 us; speedup vs baseline: 1.4629x; 1.1641x over previous
//
#include <hip/hip_runtime.h>
#include <hip/hip_bf16.h>
#include <stdint.h>

// ---------------------------------------------------------------------------
// y = w4( s1 ),  s1 = (1-g1)*h1 + z1   (s0 == 1 exactly: tanh saturation)
// R7: counted-vmcnt 2-phase pipeline -> 137us, but BK2=64 made LDS rows 128B:
//   16-way bank conflict on every ds_read_b128 (SQ_LDS_BANK_CONFLICT 22M,
//   ~26% of wall time), and with loads prefetched the ds_read chain IS the
//   critical path (MfmaUtil 18%).
// R8: T2 XOR-swizzle, gload_lds-compatible (rule #21):
//   - LDS dest linear (DMA requirement), global SOURCE chunk pre-swizzled
//     j -> j ^ (row&7)  (XOR involution)
//   - ds_read chunk c at (c ^ (row&7))*16B  -> lanes spread across all 8
//     16B slots; only the free 2-way alias remains.
// ---------------------------------------------------------------------------

typedef unsigned short u16;
using f32x4  = __attribute__((ext_vector_type(4))) float;
using bf16x8 = __attribute__((ext_vector_type(8))) short;

#define BATCH 16384
#define NIN   256
#define NHID  1024
#define NOUT  256

#define BM 128
#define BN 128
#define BK2 64   // K-chunk per pipeline step (128B rows in LDS)

__device__ __forceinline__ u16 f2bf(float f) {
  unsigned u = __builtin_bit_cast(unsigned, f);
  unsigned r = 0x7fffu + ((u >> 16) & 1u);
  return (u16)((u + r) >> 16);
}
__device__ __forceinline__ float bf2f(u16 h) {
  unsigned u = ((unsigned)h) << 16;
  return __builtin_bit_cast(float, u);
}
__device__ __forceinline__ float fast_tanh(float x) {
  float cx = fminf(fmaxf(x, -15.f), 15.f);
  float e  = __expf(2.f * cx);
  return (e - 1.f) / (e + 1.f);
}

__device__ __forceinline__ void gload_lds16(const u16* g, u16* l) {
  __builtin_amdgcn_global_load_lds(
      (__attribute__((address_space(1))) void*)(const_cast<u16*>(g)),
      (__attribute__((address_space(3))) void*)(l),
      16, 0, 0);
}

// Stage a 128x64 bf16 tile (16KB), SWIZZLED: LDS granule (row, j) holds
// global chunk (row, j ^ (row&7)). LDS dest stays linear (DMA constraint).
__device__ __forceinline__ void stage64(const u16* g0, int ld, u16* lds) {
  int t = threadIdx.x;
#pragma unroll
  for (int iss = 0; iss < 4; ++iss) {
    int idx = t + iss * 256;        // granule 0..1023
    int row = idx >> 3;             // 8 granules (128B) per row
    int j   = idx & 7;
    int c   = (j ^ (row & 7)) << 3; // pre-swizzled source chunk
    gload_lds16(g0 + (size_t)row * ld + c, lds + (size_t)idx * 8);
  }
}

// One BK2=64 step: 32 MFMA per wave. Reads apply the same XOR: chunk c of
// row r lives at LDS (row, c ^ (r&7)). row&7 == r&7 for all frags (wm/wn,
// i*16 are multiples of 16), so the XOR is computed once per ks.
__device__ __forceinline__ void mfma64(const u16* As, const u16* Bs,
                                       int wm, int wn, int lane,
                                       f32x4 acc[4][4]) {
  int r  = lane & 15;
  int q  = lane >> 4;
  int xr = r & 7;
#pragma unroll
  for (int ks = 0; ks < 2; ++ks) {
    int cx = ((ks * 4 + q) ^ xr) << 3;   // swizzled elem offset within row
    bf16x8 a[4], b[4];
#pragma unroll
    for (int i = 0; i < 4; ++i)
      a[i] = *(const bf16x8*)(As + (size_t)((wm + i * 16 + r) * BK2 + cx));
#pragma unroll
    for (int j = 0; j < 4; ++j)
      b[j] = *(const bf16x8*)(Bs + (size_t)((wn + j * 16 + r) * BK2 + cx));
#pragma unroll
    for (int i = 0; i < 4; ++i)
#pragma unroll
      for (int j = 0; j < 4; ++j)
        acc[i][j] = __builtin_amdgcn_mfma_f32_16x16x32_bf16(a[i], b[j], acc[i][j], 0, 0, 0);
  }
}

// One pipeline step: issue next-tile stage, wait CURRENT tile (vmcnt(8): next's
// 8 loads stay in flight), barrier, compute, drain own ds_reads, barrier.
__device__ __forceinline__ void pipe_step(const u16* At, int lda,
                                          const u16* Bt, int ldb,
                                          int t, int STEPS,
                                          u16* Ac, u16* Bc, u16* An, u16* Bn,
                                          int wm, int wn, int lane,
                                          f32x4 acc[4][4]) {
  if (t + 1 < STEPS) {
    stage64(At + (size_t)(t + 1) * BK2, lda, An);
    stage64(Bt + (size_t)(t + 1) * BK2, ldb, Bn);
    asm volatile("s_waitcnt vmcnt(8)" ::: "memory");
  } else {
    asm volatile("s_waitcnt vmcnt(0)" ::: "memory");
  }
  __builtin_amdgcn_s_barrier();
  mfma64(Ac, Bc, wm, wn, lane, acc);
  asm volatile("s_waitcnt lgkmcnt(0)" ::: "memory");
  __builtin_amdgcn_s_barrier();
}

// A: MxK row-major(lda), B: NxK row-major(ldb) -> acc += A@B.T (tile m0,n0).
// smem layout: As0 | Bs0 | As1 | Bs1, 8192 u16 (16KB) each.
template<int STEPS>
__device__ __forceinline__ void gemm_pipe(const u16* A, int lda,
                                          const u16* B, int ldb,
                                          int m0, int n0, u16* sm,
                                          int wm, int wn, int lane,
                                          f32x4 acc[4][4]) {
  const u16* At = A + (size_t)m0 * lda;
  const u16* Bt = B + (size_t)n0 * ldb;
  u16* As0 = sm;          u16* Bs0 = sm + 8192;
  u16* As1 = sm + 16384;  u16* Bs1 = sm + 24576;
  stage64(At, lda, As0);
  stage64(Bt, ldb, Bs0);
  static_assert(STEPS % 2 == 0, "even steps");
#pragma unroll
  for (int tt = 0; tt < STEPS / 2; ++tt) {
    pipe_step(At, lda, Bt, ldb, 2 * tt,     STEPS, As0, Bs0, As1, Bs1, wm, wn, lane, acc);
    pipe_step(At, lda, Bt, ldb, 2 * tt + 1, STEPS, As1, Bs1, As0, Bs0, wm, wn, lane, acc);
  }
}

__device__ __forceinline__ void zero_acc(f32x4 acc[4][4]) {
  f32x4 z = {0.f, 0.f, 0.f, 0.f};
#pragma unroll
  for (int i = 0; i < 4; ++i)
#pragma unroll
    for (int j = 0; j < 4; ++j) acc[i][j] = z;
}

// --------------------------- prep kernels ----------------------------------

__global__ void k_prep_x(const float* __restrict__ x, u16* __restrict__ xa) {
  int i = blockIdx.x * 256 + threadIdx.x;
  float4 v = ((const float4*)x)[i];
  ushort4 o;
  o.x = f2bf(fabsf(v.x) + 0.1f);
  o.y = f2bf(fabsf(v.y) + 0.1f);
  o.z = f2bf(fabsf(v.z) + 0.1f);
  o.w = f2bf(fabsf(v.w) + 0.1f);
  ((ushort4*)xa)[i] = o;
}

struct WCvt { const float* src[6]; u16* dst[6]; int n[6]; };
__global__ void k_cvt(WCvt a) {
  int k = blockIdx.y;
  int i = blockIdx.x * 256 + threadIdx.x;
  if (i * 4 < a.n[k]) {
    float4 v = ((const float4*)a.src[k])[i];
    ushort4 o;
    o.x = f2bf(v.x); o.y = f2bf(v.y); o.z = f2bf(v.z); o.w = f2bf(v.w);
    ((ushort4*)a.dst[k])[i] = o;
  }
}

// c[n] = sum_k W[n,k] + b[n]  (s0==1 collapse of s0@W.T)
struct WSum { const float* w[3]; const float* b[3]; float* c[3]; };
__global__ void k_wsum(WSum a) {
  int g = blockIdx.y, n = blockIdx.x;
  const float* row = a.w[g] + (size_t)n * NHID;
  float s = 0.f;
  for (int k = threadIdx.x; k < NHID; k += 256) s += row[k];
#pragma unroll
  for (int o = 32; o; o >>= 1) s += __shfl_down(s, o, 64);
  __shared__ float sm[4];
  if ((threadIdx.x & 63) == 0) sm[threadIdx.x >> 6] = s;
  __syncthreads();
  if (threadIdx.x == 0) a.c[g][n] = sm[0] + sm[1] + sm[2] + sm[3] + a.b[g][n];
}

// --------------------------- GEMM passes -----------------------------------

// r1 = tanh(xa @ ur.T + cr)
__global__ __launch_bounds__(256) void k_pass_r(const u16* __restrict__ xa,
                                                const u16* __restrict__ ur,
                                                const float* __restrict__ cr,
                                                u16* __restrict__ r1) {
  __shared__ __align__(16) u16 smem[32768];
  int m0 = blockIdx.y * BM, n0 = blockIdx.x * BN;
  int lane = threadIdx.x & 63, wave = threadIdx.x >> 6;
  int wm = (wave >> 1) * 64, wn = (wave & 1) * 64;
  f32x4 acc[4][4];
  zero_acc(acc);
  gemm_pipe<4>(xa, NIN, ur, NIN, m0, n0, smem, wm, wn, lane, acc);

  int crw = (lane >> 4) * 4, cc = lane & 15;
#pragma unroll
  for (int ni = 0; ni < 4; ++ni) {
    int col = n0 + wn + ni * 16 + cc;
    float bias = cr[col];
#pragma unroll
    for (int mi = 0; mi < 4; ++mi)
#pragma unroll
      for (int r = 0; r < 4; ++r) {
        int row = m0 + wm + mi * 16 + crw + r;
        r1[(size_t)row * NHID + col] = f2bf(fast_tanh(acc[mi][ni][r] + bias));
      }
  }
}

// Fused: pg=1-tanh(xa@ug+cg), pz=tanh(xa@uz+cz) in regs (packed bf16);
//        h=tanh(xa@uh + r1@wh + bh);  s1 = pg*h + pz.
__global__ __launch_bounds__(256) void k_gates_h(
    const u16* __restrict__ xa,
    const u16* __restrict__ ug, const u16* __restrict__ uz,
    const u16* __restrict__ uh,
    const float* __restrict__ cg, const float* __restrict__ cz,
    const float* __restrict__ bh,
    const u16* __restrict__ r1, const u16* __restrict__ wh,
    u16* __restrict__ s1) {
  __shared__ __align__(16) u16 smem[32768];

  // XCD-chunked swizzle: XCD k owns m-panels [16k,16k+16), n fastest ->
  // r1 panel (256KB) stays L2-resident across its 8 n-blocks.
  int wg  = blockIdx.x;
  int xcd = wg & 7;
  int idx = wg >> 3;
  int mb  = xcd * 16 + (idx >> 3);
  int nb  = idx & 7;
  int m0 = mb * BM, n0 = nb * BN;

  int lane = threadIdx.x & 63, wave = threadIdx.x >> 6;
  int wm = (wave >> 1) * 64, wn = (wave & 1) * 64;
  int crw = (lane >> 4) * 4, cc = lane & 15;

  f32x4 acc[4][4];
  unsigned pg[4][4][2], pz[4][4][2];   // packed bf16 pairs, static idx only

  // ---- gate g ----
  zero_acc(acc);
  gemm_pipe<4>(xa, NIN, ug, NIN, m0, n0, smem, wm, wn, lane, acc);
#pragma unroll
  for (int ni = 0; ni < 4; ++ni) {
    float cv = cg[n0 + wn + ni * 16 + cc];
#pragma unroll
    for (int mi = 0; mi < 4; ++mi) {
      float v0 = 1.f - fast_tanh(acc[mi][ni][0] + cv);
      float v1 = 1.f - fast_tanh(acc[mi][ni][1] + cv);
      float v2 = 1.f - fast_tanh(acc[mi][ni][2] + cv);
      float v3 = 1.f - fast_tanh(acc[mi][ni][3] + cv);
      pg[mi][ni][0] = (unsigned)f2bf(v0) | ((unsigned)f2bf(v1) << 16);
      pg[mi][ni][1] = (unsigned)f2bf(v2) | ((unsigned)f2bf(v3) << 16);
    }
  }

  // ---- gate z ----
  zero_acc(acc);
  gemm_pipe<4>(xa, NIN, uz, NIN, m0, n0, smem, wm, wn, lane, acc);
#pragma unroll
  for (int ni = 0; ni < 4; ++ni) {
    float cv = cz[n0 + wn + ni * 16 + cc];
#pragma unroll
    for (int mi = 0; mi < 4; ++mi) {
      float v0 = fast_tanh(acc[mi][ni][0] + cv);
      float v1 = fast_tanh(acc[mi][ni][1] + cv);
      float v2 = fast_tanh(acc[mi][ni][2] + cv);
      float v3 = fast_tanh(acc[mi][ni][3] + cv);
      pz[mi][ni][0] = (unsigned)f2bf(v0) | ((unsigned)f2bf(v1) << 16);
      pz[mi][ni][1] = (unsigned)f2bf(v2) | ((unsigned)f2bf(v3) << 16);
    }
  }

  // ---- h ----
  zero_acc(acc);
  gemm_pipe<4>(xa, NIN, uh, NIN, m0, n0, smem, wm, wn, lane, acc);
  gemm_pipe<16>(r1, NHID, wh, NHID, m0, n0, smem, wm, wn, lane, acc);

#pragma unroll
  for (int ni = 0; ni < 4; ++ni) {
    int col = n0 + wn + ni * 16 + cc;
    float bias = bh[col];
#pragma unroll
    for (int mi = 0; mi < 4; ++mi)
#pragma unroll
      for (int r = 0; r < 4; ++r) {
        int row = m0 + wm + mi * 16 + crw + r;
        float h = fast_tanh(acc[mi][ni][r] + bias);
        unsigned pgw = pg[mi][ni][r >> 1];
        unsigned pzw = pz[mi][ni][r >> 1];
        u16 pgh = (r & 1) ? (u16)(pgw >> 16) : (u16)(pgw & 0xffff);
        u16 pzh = (r & 1) ? (u16)(pzw >> 16) : (u16)(pzw & 0xffff);
        float s = bf2f(pgh) * h + bf2f(pzh);
        s1[(size_t)row * NHID + col] = f2bf(s);
      }
  }
}

// y = s1 @ w4.T (fp32 out)
__global__ __launch_bounds__(256) void k_pass_c(const u16* __restrict__ s1,
                                                const u16* __restrict__ w4,
                                                float* __restrict__ y) {
  __shared__ __align__(16) u16 smem[32768];
  int m0 = blockIdx.y * BM, n0 = blockIdx.x * BN;
  int lane = threadIdx.x & 63, wave = threadIdx.x >> 6;
  int wm = (wave >> 1) * 64, wn = (wave & 1) * 64;
  f32x4 acc[4][4];
  zero_acc(acc);
  gemm_pipe<16>(s1, NHID, w4, NHID, m0, n0, smem, wm, wn, lane, acc);

  int crw = (lane >> 4) * 4, cc = lane & 15;
#pragma unroll
  for (int ni = 0; ni < 4; ++ni) {
    int col = n0 + wn + ni * 16 + cc;
#pragma unroll
    for (int mi = 0; mi < 4; ++mi)
#pragma unroll
      for (int r = 0; r < 4; ++r) {
        int row = m0 + wm + mi * 16 + crw + r;
        y[(size_t)row * NOUT + col] = acc[mi][ni][r];
      }
  }
}

// --------------------------- host ------------------------------------------

extern "C" void kernel_launch(void* const* d_in, const int* in_sizes, int n_in,
                              void* d_out, int out_size, void* d_ws, size_t ws_size,
                              hipStream_t stream) {
  (void)in_sizes; (void)n_in; (void)out_size; (void)ws_size;

  const float* x    = (const float*)d_in[0];
  const float* ug1  = (const float*)d_in[3];
  const float* wg1w = (const float*)d_in[4];
  const float* wg1b = (const float*)d_in[5];
  const float* uz1  = (const float*)d_in[6];
  const float* wz1w = (const float*)d_in[7];
  const float* wz1b = (const float*)d_in[8];
  const float* ur1  = (const float*)d_in[9];
  const float* wr1w = (const float*)d_in[10];
  const float* wr1b = (const float*)d_in[11];
  const float* uh1  = (const float*)d_in[12];
  const float* wh1w = (const float*)d_in[13];
  const float* wh1b = (const float*)d_in[14];
  const float* w4   = (const float*)d_in[27];
  float* y = (float*)d_out;

  uint8_t* ws = (uint8_t*)d_ws;
  size_t off = 0;
  auto carve = [&](size_t bytes) -> void* {
    void* p = ws + off;
    off += (bytes + 255) & ~(size_t)255;
    return p;
  };
  u16* xa  = (u16*)carve((size_t)BATCH * NIN * 2);    //  8 MB
  u16* r1  = (u16*)carve((size_t)BATCH * NHID * 2);   // 32 MB
  u16* s1  = (u16*)carve((size_t)BATCH * NHID * 2);   // 32 MB
  u16* bug = (u16*)carve((size_t)NHID * NIN * 2);
  u16* buz = (u16*)carve((size_t)NHID * NIN * 2);
  u16* bur = (u16*)carve((size_t)NHID * NIN * 2);
  u16* buh = (u16*)carve((size_t)NHID * NIN * 2);
  u16* bwh = (u16*)carve((size_t)NHID * NHID * 2);
  u16* bw4 = (u16*)carve((size_t)NOUT * NHID * 2);
  float* cg = (float*)carve(NHID * 4);
  float* cz = (float*)carve(NHID * 4);
  float* cr = (float*)carve(NHID * 4);

  k_prep_x<<<(BATCH * NIN) / (256 * 4), 256, 0, stream>>>(x, xa);

  WCvt wc;
  wc.src[0] = ug1;  wc.dst[0] = bug; wc.n[0] = NHID * NIN;
  wc.src[1] = uz1;  wc.dst[1] = buz; wc.n[1] = NHID * NIN;
  wc.src[2] = ur1;  wc.dst[2] = bur; wc.n[2] = NHID * NIN;
  wc.src[3] = uh1;  wc.dst[3] = buh; wc.n[3] = NHID * NIN;
  wc.src[4] = wh1w; wc.dst[4] = bwh; wc.n[4] = NHID * NHID;
  wc.src[5] = w4;   wc.dst[5] = bw4; wc.n[5] = NOUT * NHID;
  k_cvt<<<dim3(1024, 6), 256, 0, stream>>>(wc);

  WSum wsm;
  wsm.w[0] = wg1w; wsm.b[0] = wg1b; wsm.c[0] = cg;
  wsm.w[1] = wz1w; wsm.b[1] = wz1b; wsm.c[1] = cz;
  wsm.w[2] = wr1w; wsm.b[2] = wr1b; wsm.c[2] = cr;
  k_wsum<<<dim3(1024, 3), 256, 0, stream>>>(wsm);

  k_pass_r<<<dim3(NHID / BN, BATCH / BM), 256, 0, stream>>>(xa, bur, cr, r1);

  k_gates_h<<<(NHID / BN) * (BATCH / BM), 256, 0, stream>>>(
      xa, bug, buz, buh, cg, cz, wh1b, r1, bwh, s1);

  k_pass_c<<<dim3(NOUT / BN, BATCH / BM), 256, 0, stream>>>(s1, bw4, y);
}